// Round 8
// baseline (51.844 us; speedup 1.0000x reference)
//
#include <hip/hip_runtime.h>

typedef int int4v __attribute__((ext_vector_type(4)));

// Problem constants
#define IN_C    64
#define OUT_C   128
#define KTOT    576
#define N_X     12845056    // x elements (int32) = x8 bytes
#define N_W     73728       // 128*3*3*64
#define N_OUT   25690112
#define NTILES  3136        // 64 images x 7x7 tiles

// prep grid split
#define PW_BLKS 72          // 18432 dwords of packed weights
#define PX_BLKS 12544       // 3211264 dwords of packed x

__device__ __forceinline__ int pack4(int4v a) {
    return (a.x & 0xff) | ((a.y & 0xff) << 8) | ((a.z & 0xff) << 16) | (a.w << 24);
}

// ---------------------------------------------------------------------------
// Fused prep: pack weights into MFMA fragment order AND x into int8 NHWC.
//   w8 dest byte t = ((kt*8 + nt)*64 + lane)*16 + byte
//     holds W[k][n], k = kt*64 + (lane>>4)*16 + byte, n = nt*16 + (lane&15)
//   x8 is a straight int32 -> int8 narrowing of NHWC x.
__global__ __launch_bounds__(256) void prep_kernel(const int* __restrict__ x,
                                                   const int* __restrict__ wgt,
                                                   unsigned int* __restrict__ x8,
                                                   unsigned int* __restrict__ w8) {
    const int bid = blockIdx.x;
    if (bid < PW_BLKS) {
        int t = bid * 256 + threadIdx.x;      // t < 18432
        int d = t << 2;
        int byte = d & 15;
        int lane = (d >> 4) & 63;
        int ntk  = d >> 10;
        int nt   = ntk & 7;
        int kt   = ntk >> 3;
        int k = kt * 64 + ((lane >> 4) << 4) + byte;
        int n = nt * 16 + (lane & 15);
        int4v v = *(const int4v*)(wgt + n * KTOT + k);
        w8[t] = pack4(v);
    } else {
        int i = (bid - PW_BLKS) * 256 + threadIdx.x;   // i < 3211264 exactly
        int4v v = ((const int4v*)x)[i];
        x8[i] = pack4(v);
    }
}

// ---------------------------------------------------------------------------
// DMA halo-tile MFMA conv. Block = 8x8 pixels x 128 channels, 4 waves.
// Halo (10x10 px x 64B int8 = 6400B) staged via global_load_lds (async DMA,
// no staging regs/VALU). A = weights (M=channels), B = x pixels (N=pixels)
// -> D row = channel -> dwordx4 epilogue stores.
__global__ __launch_bounds__(256, 5) void conv_dma_kernel(const char* __restrict__ x8,
                                                          const char* __restrict__ w8,
                                                          const int* __restrict__ bias,
                                                          int* __restrict__ out) {
    __shared__ char hx[100 * 64];

    const int tid  = threadIdx.x;
    const int lane = tid & 63;
    const int wv   = tid >> 6;
    const int l15  = lane & 15;
    const int l4   = lane >> 4;

    // XCD-chunked bijective swizzle: 3136 = 8 XCDs x 392 (8 whole images).
    const int bid = blockIdx.x;
    const int nb  = (bid & 7) * 392 + (bid >> 3);

    const int n   = nb / 49;
    const int rr  = nb - n * 49;
    const int th  = rr / 7;
    const int tw  = rr - th * 7;
    const int h0  = th * 8 - 1;
    const int w0  = tw * 8 - 1;

    // ---- DMA staging: 400 units of 16B. LDS dest is linear unit*16;
    // instr0: wave w -> units [w*64, w*64+64), base hx + w*1024.
    // instr1: wave w -> units [256+w*36, +36), base hx + 4096 + w*576 (lane<36).
    const int px0 = (wv << 4) + (lane >> 2);       // unit0>>2
    const int q0  = lane & 3;
    const int hr0 = px0 / 10, hc0 = px0 - hr0 * 10;
    const int gh0 = h0 + hr0, gw0 = w0 + hc0;
    const bool ok0 = ((unsigned)gh0 < 56u) & ((unsigned)gw0 < 56u);

    const int unit1 = 256 + wv * 36 + lane;
    const int px1 = unit1 >> 2;                    // (unit1&3) == q0
    const int hr1 = px1 / 10, hc1 = px1 - hr1 * 10;
    const int gh1 = h0 + hr1, gw1 = w0 + hc1;
    const bool ok1 = (lane < 36) & ((unsigned)gh1 < 56u) & ((unsigned)gw1 < 56u);

    // Border blocks: pre-zero this thread's DMA slots (masked lanes keep 0).
    const bool border = (th == 0) | (th == 6) | (tw == 0) | (tw == 6);
    if (border) {
        int4v z = {0, 0, 0, 0};
        *(int4v*)(hx + (((wv << 6) + lane) << 4)) = z;
        if (lane < 36) *(int4v*)(hx + (unit1 << 4)) = z;
        asm volatile("s_waitcnt lgkmcnt(0)" ::: "memory");
    }

    if (ok0)
        __builtin_amdgcn_global_load_lds(
            (const __attribute__((address_space(1))) void*)
                (x8 + (((n * 3136 + gh0 * 56 + gw0) << 6) + (q0 << 4))),
            (__attribute__((address_space(3))) void*)(hx + (wv << 10)),
            16, 0, 0);
    if (ok1)
        __builtin_amdgcn_global_load_lds(
            (const __attribute__((address_space(1))) void*)
                (x8 + (((n * 3136 + gh1 * 56 + gw1) << 6) + (q0 << 4))),
            (__attribute__((address_space(3))) void*)(hx + 4096 + wv * 576),
            16, 0, 0);
    __builtin_amdgcn_sched_barrier(0);

    // ---- Depth-4 weight preload while DMA is in flight.
    const char* wb = w8 + (((wv * 2) * 64 + lane) << 4);
    int4v bR[4][2];
#pragma unroll
    for (int i = 0; i < 4; ++i) {
        bR[i][0] = *(const int4v*)(wb);
        bR[i][1] = *(const int4v*)(wb + 1024);
        wb += 8192;
    }
    __builtin_amdgcn_sched_barrier(0);

    __syncthreads();   // drains vmcnt (DMA + weight preload) + lgkm

    // ---- Compute: rolling 4-deep weight prefetch, fully unrolled kt loop.
    // Pixel operand: halo px = mt*20 + (l15>>3)*10 + (l15&7), ic-quarter l4.
    const char* ap = hx + (((l15 >> 3) * 10 + (l15 & 7)) << 6) + (l4 << 4);

    int4v acc[4][2];
#pragma unroll
    for (int mt = 0; mt < 4; ++mt) {
        acc[mt][0] = (int4v){0, 0, 0, 0};
        acc[mt][1] = (int4v){0, 0, 0, 0};
    }

    int toff = 0;                                  // kh*640 + kw*64
#pragma unroll
    for (int kt = 0; kt < 9; ++kt) {
        int4v c0 = bR[kt & 3][0];
        int4v c1 = bR[kt & 3][1];
        if (kt < 5) {                              // prefetch kt+4
            bR[kt & 3][0] = *(const int4v*)(wb);
            bR[kt & 3][1] = *(const int4v*)(wb + 1024);
            wb += 8192;
        }
#pragma unroll
        for (int mt = 0; mt < 4; ++mt) {
            int4v a = *(const int4v*)(ap + toff + mt * 1280);
            acc[mt][0] = __builtin_amdgcn_mfma_i32_16x16x64_i8(c0, a, acc[mt][0], 0, 0, 0);
            acc[mt][1] = __builtin_amdgcn_mfma_i32_16x16x64_i8(c1, a, acc[mt][1], 0, 0, 0);
        }
        toff += 64;
        if ((kt == 2) | (kt == 5)) toff += 448;
    }

    // ---- Epilogue: lane holds 4 consecutive channels -> dwordx4 stores.
    const int chb = wv * 32 + (l4 << 2);
    int4v bv0 = *(const int4v*)(bias + chb);
    int4v bv1 = *(const int4v*)(bias + chb + 16);
    int* ob = out + (((n * 56 + th * 8) * 56 + tw * 8) << 7);
    const int pc = l15 & 7;
    const int prl = l15 >> 3;
#pragma unroll
    for (int mt = 0; mt < 4; ++mt) {
        int pr = (mt << 1) + prl;
        int* o = ob + ((pr * 56 + pc) << 7) + chb;
        *(int4v*)(o)      = acc[mt][0] + bv0;
        *(int4v*)(o + 16) = acc[mt][1] + bv1;
    }
}

// ---------------------------------------------------------------------------
// Fallback (only if workspace is too small): direct conv, 1 thread/output.
__global__ __launch_bounds__(256) void conv_naive_kernel(const int* __restrict__ x,
                                                         const int* __restrict__ wgt,
                                                         const int* __restrict__ bias,
                                                         int* __restrict__ out) {
    int idx = blockIdx.x * 256 + threadIdx.x;
    if (idx >= N_OUT) return;
    int ch  = idx & 127;
    int pix = idx >> 7;
    int n  = pix / 3136;
    int r2 = pix - n * 3136;
    int h  = r2 / 56;
    int w  = r2 - h * 56;
    int acc = bias[ch];
    for (int kh = 0; kh < 3; ++kh) {
        int hxr = h + kh - 1;
        if ((unsigned)hxr >= 56u) continue;
        for (int kw = 0; kw < 3; ++kw) {
            int wx = w + kw - 1;
            if ((unsigned)wx >= 56u) continue;
            const int* xp = x + ((n * 56 + hxr) * 56 + wx) * 64;
            const int* wp = wgt + ch * KTOT + (kh * 3 + kw) * 64;
            for (int ic = 0; ic < 64; ++ic) acc += xp[ic] * wp[ic];
        }
    }
    out[idx] = acc;
}

// ---------------------------------------------------------------------------
extern "C" void kernel_launch(void* const* d_in, const int* in_sizes, int n_in,
                              void* d_out, int out_size, void* d_ws, size_t ws_size,
                              hipStream_t stream) {
    const int* x    = (const int*)d_in[0];
    const int* wgt  = (const int*)d_in[1];
    const int* bias = (const int*)d_in[2];
    int* out = (int*)d_out;

    const size_t need = (size_t)N_X + (size_t)N_W;   // 12,918,784 B
    if (ws_size >= need) {
        char* x8 = (char*)d_ws;              // N_X bytes, int8 NHWC
        char* w8 = (char*)d_ws + N_X;        // N_W bytes, fragment order
        prep_kernel<<<PW_BLKS + PX_BLKS, 256, 0, stream>>>(x, wgt,
                                                           (unsigned int*)x8,
                                                           (unsigned int*)w8);
        conv_dma_kernel<<<NTILES, 256, 0, stream>>>(x8, w8, bias, out);
    } else {
        conv_naive_kernel<<<(N_OUT + 255) / 256, 256, 0, stream>>>(x, wgt, bias, out);
    }
}